// Round 2
// baseline (158.386 us; speedup 1.0000x reference)
//
#include <hip/hip_runtime.h>
#include <hip/hip_bf16.h>

// Problem constants (from reference)
#define NNODES 10000
#define DDEG   64
#define NEDGES 32768
#define FIN    64
#define HID    256

typedef __attribute__((ext_vector_type(8))) __bf16 bf16x8;
typedef __attribute__((ext_vector_type(4))) float  f32x4;

__device__ __forceinline__ unsigned short f2bf(float f) {
    unsigned x = __float_as_uint(f);
    unsigned r = (x + 0x7FFFu + ((x >> 16) & 1u)) >> 16;  // RNE
    return (unsigned short)r;
}

// Transpose weight W[K,256] (fp32 row-major) -> WT[256,K] (bf16 row-major)
__global__ __launch_bounds__(256) void transpose_k(const float* __restrict__ src,
                                                   unsigned short* __restrict__ dst,
                                                   int kshift, int total) {
    int idx = blockIdx.x * 256 + threadIdx.x;
    if (idx >= total) return;
    int k = idx & ((1 << kshift) - 1);
    int n = idx >> kshift;
    dst[idx] = f2bf(src[k * HID + n]);
}

// One wave per edge: membership mask + xij + xcn gather-sum. x is fp32.
__global__ __launch_bounds__(256) void edge_k(const float* __restrict__ x,
                                              const int* __restrict__ adj,
                                              const int* __restrict__ tar,
                                              unsigned short* __restrict__ xij,
                                              unsigned short* __restrict__ xcn) {
    int w    = threadIdx.x >> 6;
    int lane = threadIdx.x & 63;
    int e    = blockIdx.x * 4 + w;           // grid = NEDGES/4 exactly

    int i = tar[e];
    int j = tar[NEDGES + e];

    int ni = adj[i * DDEG + lane];
    int nj = adj[j * DDEG + lane];

    bool found = false;
#pragma unroll
    for (int b = 0; b < 64; ++b) found |= (ni == __shfl(nj, b));
    unsigned long long m = __ballot(found);

    float xi = x[i * FIN + lane];
    float xj = x[j * FIN + lane];
    xij[(size_t)e * FIN + lane] = f2bf(xi * xj);

    float acc = 0.f;
    while (m) {
        int a = __ffsll(m) - 1;
        m &= m - 1;
        int row = __shfl(ni, a);
        acc += x[row * FIN + lane];
    }
    xcn[(size_t)e * FIN + lane] = f2bf(acc);
}

// C[M,256] = act(A[M,K] @ W[K,256] + bias) with optional epilogues. A,C bf16; bias fp32.
// Block: 256 threads = 4 waves; block computes 64 rows x 256 cols.
// Wave wv -> cols [wv*64, wv*64+64). 4x4 fragments of mfma_f32_16x16x32_bf16.
// A-frag lane l: A[row0+m*16+(l&15)][kk+8*(l>>4)+i]   (contiguous 16B)
// B-frag lane l: WT[col0+n*16+(l&15)][kk+8*(l>>4)+i]  (WT = W^T, bf16 [256][K])
// D lane l: row=(l>>4)*4+reg, col=l&15.
// In-place A==C is safe: __syncthreads() separates all A reads from C writes,
// and a block only writes rows that only it reads.
template <int K, bool RELU, bool BETAADD, bool FINAL>
__global__ __launch_bounds__(256) void gemm_k(const unsigned short* __restrict__ A,
                                              const unsigned short* __restrict__ WT,
                                              const float* __restrict__ bias,
                                              unsigned short* __restrict__ C,
                                              const unsigned short* __restrict__ S,
                                              const float* __restrict__ beta,
                                              const float* __restrict__ w2,
                                              float* __restrict__ part) {
    int wv   = threadIdx.x >> 6;
    int lane = threadIdx.x & 63;
    int lr   = lane & 15;
    int lg   = lane >> 4;
    int row0 = blockIdx.x * 64;
    int col0 = wv * 64;

    f32x4 acc[4][4];
#pragma unroll
    for (int m = 0; m < 4; ++m)
#pragma unroll
        for (int n = 0; n < 4; ++n) acc[m][n] = (f32x4){0.f, 0.f, 0.f, 0.f};

    const unsigned short* pa[4];
    const unsigned short* pb[4];
#pragma unroll
    for (int m = 0; m < 4; ++m) pa[m] = A + (size_t)(row0 + m * 16 + lr) * K + 8 * lg;
#pragma unroll
    for (int n = 0; n < 4; ++n) pb[n] = WT + (size_t)(col0 + n * 16 + lr) * K + 8 * lg;

    for (int kk = 0; kk < K; kk += 32) {
        bf16x8 a[4], b[4];
#pragma unroll
        for (int m = 0; m < 4; ++m) a[m] = *reinterpret_cast<const bf16x8*>(pa[m] + kk);
#pragma unroll
        for (int n = 0; n < 4; ++n) b[n] = *reinterpret_cast<const bf16x8*>(pb[n] + kk);
#pragma unroll
        for (int m = 0; m < 4; ++m)
#pragma unroll
            for (int n = 0; n < 4; ++n)
                acc[m][n] = __builtin_amdgcn_mfma_f32_16x16x32_bf16(a[m], b[n], acc[m][n], 0, 0, 0);
    }

    __syncthreads();   // all A reads complete before any C write (enables in-place)

    float bl[4];
#pragma unroll
    for (int n = 0; n < 4; ++n) bl[n] = bias[col0 + n * 16 + lr];

    float w2l[4] = {0.f, 0.f, 0.f, 0.f};
    if constexpr (FINAL) {
#pragma unroll
        for (int n = 0; n < 4; ++n) w2l[n] = w2[col0 + n * 16 + lr];
    }
    float betaf = 0.f;
    if constexpr (BETAADD) betaf = beta[0];

#pragma unroll
    for (int m = 0; m < 4; ++m) {
        float p[4] = {0.f, 0.f, 0.f, 0.f};
#pragma unroll
        for (int n = 0; n < 4; ++n) {
#pragma unroll
            for (int i = 0; i < 4; ++i) {
                float v = acc[m][n][i] + bl[n];
                if constexpr (RELU) v = fmaxf(v, 0.f);
                int row = row0 + m * 16 + 4 * lg + i;
                int col = col0 + n * 16 + lr;
                if constexpr (BETAADD) {
                    float s = __uint_as_float(((unsigned)S[(size_t)row * HID + col]) << 16);
                    v = v * betaf + s;
                }
                if constexpr (FINAL) {
                    p[i] += v * w2l[n];
                } else {
                    C[(size_t)row * HID + col] = f2bf(v);
                }
            }
        }
        if constexpr (FINAL) {
#pragma unroll
            for (int i = 0; i < 4; ++i) {
                float s = p[i];
                s += __shfl_xor(s, 1);
                s += __shfl_xor(s, 2);
                s += __shfl_xor(s, 4);
                s += __shfl_xor(s, 8);
                if (lr == 0) part[(size_t)wv * NEDGES + (row0 + m * 16 + 4 * lg + i)] = s;
            }
        }
    }
}

__global__ __launch_bounds__(256) void final_k(const float* __restrict__ part,
                                               const float* __restrict__ b2,
                                               float* __restrict__ out) {
    int e = blockIdx.x * 256 + threadIdx.x;   // grid = NEDGES/256 exactly
    out[e] = part[e] + part[NEDGES + e] + part[2 * NEDGES + e] + part[3 * NEDGES + e] + b2[0];
}

extern "C" void kernel_launch(void* const* d_in, const int* in_sizes, int n_in,
                              void* d_out, int out_size, void* d_ws, size_t ws_size,
                              hipStream_t stream) {
    const float* x      = (const float*)d_in[0];
    const int*   adj    = (const int*)d_in[1];
    const int*   tar    = (const int*)d_in[2];
    const float* beta   = (const float*)d_in[3];
    const float* xcn_w1 = (const float*)d_in[4];
    const float* xcn_b1 = (const float*)d_in[5];
    const float* xcn_w2 = (const float*)d_in[6];
    const float* xcn_b2 = (const float*)d_in[7];
    const float* xcn_w3 = (const float*)d_in[8];
    const float* xcn_b3 = (const float*)d_in[9];
    const float* xij_w1 = (const float*)d_in[10];
    const float* xij_b1 = (const float*)d_in[11];
    const float* xij_w2 = (const float*)d_in[12];
    const float* xij_b2 = (const float*)d_in[13];
    const float* lin_w1 = (const float*)d_in[14];
    const float* lin_b1 = (const float*)d_in[15];
    const float* lin_w2 = (const float*)d_in[16];
    const float* lin_b2 = (const float*)d_in[17];

    char* ws = (char*)d_ws;
    unsigned short* WT_xcn1 = (unsigned short*)(ws + 0);         //  32768 B
    unsigned short* WT_xcn2 = (unsigned short*)(ws + 32768);     // 131072 B
    unsigned short* WT_xcn3 = (unsigned short*)(ws + 163840);    // 131072 B
    unsigned short* WT_xij1 = (unsigned short*)(ws + 294912);    //  32768 B
    unsigned short* WT_xij2 = (unsigned short*)(ws + 327680);    // 131072 B
    unsigned short* WT_lin1 = (unsigned short*)(ws + 458752);    // 131072 B
    unsigned short* xij     = (unsigned short*)(ws + 589824);    // 4 MiB
    unsigned short* xcn     = (unsigned short*)(ws + 4784128);   // 4 MiB
    unsigned short* P0      = (unsigned short*)(ws + 8978432);   // 16 MiB (xij branch)
    unsigned short* P1      = (unsigned short*)(ws + 25755648);  // 16 MiB (xcn branch)
    float*          part    = (float*)(ws + 42532864);           // 512 KiB
    // total: 43,057,152 B (~41 MiB)

    // Weight transposes: fp32 W[K,256] -> bf16 WT[256,K]
    transpose_k<<<64, 256, 0, stream>>>(xcn_w1, WT_xcn1, 6, FIN * HID);
    transpose_k<<<256, 256, 0, stream>>>(xcn_w2, WT_xcn2, 8, HID * HID);
    transpose_k<<<256, 256, 0, stream>>>(xcn_w3, WT_xcn3, 8, HID * HID);
    transpose_k<<<64, 256, 0, stream>>>(xij_w1, WT_xij1, 6, FIN * HID);
    transpose_k<<<256, 256, 0, stream>>>(xij_w2, WT_xij2, 8, HID * HID);
    transpose_k<<<256, 256, 0, stream>>>(lin_w1, WT_lin1, 8, HID * HID);

    // Edge stage: xij, xcn (bf16)
    edge_k<<<NEDGES / 4, 256, 0, stream>>>(x, adj, tar, xij, xcn);

    // h1_ij = relu(xij @ xij_w1 + b1)            -> P0
    gemm_k<FIN, true, false, false><<<NEDGES / 64, 256, 0, stream>>>(
        xij, WT_xij1, xij_b1, P0, nullptr, nullptr, nullptr, nullptr);
    // h_ij = h1_ij @ xij_w2 + b2                 -> P0 (in place)
    gemm_k<HID, false, false, false><<<NEDGES / 64, 256, 0, stream>>>(
        P0, WT_xij2, xij_b2, P0, nullptr, nullptr, nullptr, nullptr);
    // t1 = relu(xcn @ xcn_w1 + b1)               -> P1
    gemm_k<FIN, true, false, false><<<NEDGES / 64, 256, 0, stream>>>(
        xcn, WT_xcn1, xcn_b1, P1, nullptr, nullptr, nullptr, nullptr);
    // t2 = relu(t1 @ xcn_w2 + b2)                -> P1 (in place)
    gemm_k<HID, true, false, false><<<NEDGES / 64, 256, 0, stream>>>(
        P1, WT_xcn2, xcn_b2, P1, nullptr, nullptr, nullptr, nullptr);
    // u = (t2 @ xcn_w3 + b3) * beta + h_ij       -> P1 (in place, S = P0)
    gemm_k<HID, false, true, false><<<NEDGES / 64, 256, 0, stream>>>(
        P1, WT_xcn3, xcn_b3, P1, P0, beta, nullptr, nullptr);
    // partials: relu(u @ lin_w1 + lb1) . lin_w2  -> part (per-wave column partials)
    gemm_k<HID, true, false, true><<<NEDGES / 64, 256, 0, stream>>>(
        P1, WT_lin1, lin_b1, nullptr, nullptr, nullptr, lin_w2, part);

    final_k<<<NEDGES / 256, 256, 0, stream>>>(part, lin_b2, (float*)d_out);
}

// Round 3
// 95.603 us; speedup vs baseline: 1.6567x; 1.6567x over previous
//
#include <hip/hip_runtime.h>

// Problem constants (from reference)
#define NNODES 10000
#define DDEG   64
#define NEDGES 32768
#define FIN    64
#define HID    256

typedef __attribute__((ext_vector_type(8))) __bf16 bf16x8;
typedef __attribute__((ext_vector_type(4))) float  f32x4;

__device__ __forceinline__ unsigned short f2bf(float f) {
    unsigned x = __float_as_uint(f);
    return (unsigned short)((x + 0x7FFFu + ((x >> 16) & 1u)) >> 16);  // RNE
}
__device__ __forceinline__ float b2f(unsigned short u) {
    return __uint_as_float(((unsigned)u) << 16);
}

// Transposed-weight workspace layout (bf16 elements): WT[n][k] = W[k][n]
#define OFF_XIJ1 0        // [256][64]
#define OFF_XIJ2 16384    // [256][256]
#define OFF_XCN1 81920    // [256][64]
#define OFF_XCN2 98304    // [256][256]
#define OFF_XCN3 163840   // [256][256]
#define OFF_LIN1 229376   // [256][256]
#define WT_TOTAL 294912

// All 6 weight transposes (fp32 W[K,256] -> bf16 WT[256,K]) in ONE launch.
__global__ __launch_bounds__(256) void prep_k(const float* __restrict__ xij_w1,
                                              const float* __restrict__ xij_w2,
                                              const float* __restrict__ xcn_w1,
                                              const float* __restrict__ xcn_w2,
                                              const float* __restrict__ xcn_w3,
                                              const float* __restrict__ lin_w1,
                                              unsigned short* __restrict__ WT) {
    int idx = blockIdx.x * 256 + threadIdx.x;          // grid 1152 -> 294912
    const float* src;
    int r, ks;
    if (idx < OFF_XIJ2)      { r = idx - OFF_XIJ1; ks = 6; src = xij_w1; }
    else if (idx < OFF_XCN1) { r = idx - OFF_XIJ2; ks = 8; src = xij_w2; }
    else if (idx < OFF_XCN2) { r = idx - OFF_XCN1; ks = 6; src = xcn_w1; }
    else if (idx < OFF_XCN3) { r = idx - OFF_XCN2; ks = 8; src = xcn_w2; }
    else if (idx < OFF_LIN1) { r = idx - OFF_XCN3; ks = 8; src = xcn_w3; }
    else                     { r = idx - OFF_LIN1; ks = 8; src = lin_w1; }
    int n = r >> ks;
    int k = r & ((1 << ks) - 1);
    WT[idx] = f2bf(src[k * HID + n]);
}

// K-loop: acc[4][4] (+)= A_lds[64xK] @ WT[col-slice][K]^T via mfma_f32_16x16x32_bf16.
// A-frag lane l: row = m*16 + (l&15), k = kk + 8*(l>>4) + i. LDS is XOR-swizzled:
// element index ^= (row&7)<<3  (16B-granular; spreads the stride-K row read
// uniformly 8 lanes / 16B slot = LDS BW floor, no serializing conflicts).
template <int K>
__device__ __forceinline__ void mfma_stage(const unsigned short* As,
                                           const unsigned short* __restrict__ Wt,
                                           int lr, int lg, int col0,
                                           f32x4 acc[4][4]) {
#pragma unroll
    for (int m = 0; m < 4; ++m)
#pragma unroll
        for (int n = 0; n < 4; ++n) acc[m][n] = (f32x4){0.f, 0.f, 0.f, 0.f};
    const int sw = (lr & 7) << 3;
#pragma unroll
    for (int kk = 0; kk < K; kk += 32) {
        bf16x8 a[4], b[4];
#pragma unroll
        for (int m = 0; m < 4; ++m)
            a[m] = *reinterpret_cast<const bf16x8*>(&As[(m * 16 + lr) * K + ((kk + 8 * lg) ^ sw)]);
#pragma unroll
        for (int n = 0; n < 4; ++n)
            b[n] = *reinterpret_cast<const bf16x8*>(&Wt[(col0 + n * 16 + lr) * K + kk + 8 * lg]);
#pragma unroll
        for (int m = 0; m < 4; ++m)
#pragma unroll
            for (int n = 0; n < 4; ++n)
                acc[m][n] = __builtin_amdgcn_mfma_f32_16x16x32_bf16(a[m], b[n], acc[m][n], 0, 0, 0);
    }
}

// Fused per-64-edge pipeline: edge stage + 6 GEMM stages, intermediates in LDS.
// Block = 256 threads = 4 waves; wave wv owns output cols [wv*64, wv*64+64).
// D-frag lane l: row = m*16 + 4*(l>>4) + i, col = col0 + n*16 + (l&15).
__global__ __launch_bounds__(256, 2) void fused_k(const float* __restrict__ x,
                                                  const int* __restrict__ adj,
                                                  const int* __restrict__ tar,
                                                  const unsigned short* __restrict__ WT,
                                                  const float* __restrict__ xij_b1,
                                                  const float* __restrict__ xij_b2,
                                                  const float* __restrict__ xcn_b1,
                                                  const float* __restrict__ xcn_b2,
                                                  const float* __restrict__ xcn_b3,
                                                  const float* __restrict__ lin_b1,
                                                  const float* __restrict__ lin_w2,
                                                  const float* __restrict__ lin_b2,
                                                  const float* __restrict__ beta,
                                                  float* __restrict__ out) {
    __shared__ unsigned short sXij[64 * 64];   // 8 KB, swizzled
    __shared__ unsigned short sXcn[64 * 64];   // 8 KB, swizzled
    __shared__ unsigned short sH[64 * 256];    // 32 KB, swizzled, reused across stages
    __shared__ float sRed[4 * 64];             // 1 KB

    const int tid  = threadIdx.x;
    const int wv   = tid >> 6;
    const int lane = tid & 63;
    const int lr   = lane & 15;
    const int lg   = lane >> 4;
    const int col0 = wv * 64;
    const int row0 = blockIdx.x * 64;

    // ---- edge stage: 16 edges per wave (membership + xij + xcn gather) ----
    for (int t = 0; t < 16; ++t) {
        int el = wv * 16 + t;
        int e  = row0 + el;
        int i  = tar[e];
        int j  = tar[NEDGES + e];
        int ni = adj[i * DDEG + lane];
        int nj = adj[j * DDEG + lane];
        bool found = false;
#pragma unroll
        for (int b = 0; b < 64; ++b)
            found |= (ni == (int)__builtin_amdgcn_readlane(nj, b));
        unsigned long long m = __ballot(found);
        float acc = 0.f;
        while (m) {
            int a = __ffsll(m) - 1;
            m &= m - 1;
            int r = (int)__builtin_amdgcn_readlane(ni, a);
            acc += x[r * FIN + lane];
        }
        int sidx = el * FIN + (lane ^ ((el & 7) << 3));
        sXij[sidx] = f2bf(x[i * FIN + lane] * x[j * FIN + lane]);
        sXcn[sidx] = f2bf(acc);
    }
    __syncthreads();

    f32x4 acc[4][4];
    float bl[4];

    // ---- S1: h1 = relu(xij @ xij_w1 + b1) -> sH ----
    mfma_stage<64>(sXij, WT + OFF_XIJ1, lr, lg, col0, acc);
#pragma unroll
    for (int n = 0; n < 4; ++n) bl[n] = xij_b1[col0 + n * 16 + lr];
#pragma unroll
    for (int m = 0; m < 4; ++m)
#pragma unroll
        for (int n = 0; n < 4; ++n)
#pragma unroll
            for (int i = 0; i < 4; ++i) {
                int row = m * 16 + 4 * lg + i;
                int col = col0 + n * 16 + lr;
                sH[row * HID + (col ^ ((row & 7) << 3))] = f2bf(fmaxf(acc[m][n][i] + bl[n], 0.f));
            }
    __syncthreads();

    // ---- S2: h_ij = h1 @ xij_w2 + b2 -> registers (packed bf16) ----
    mfma_stage<256>(sH, WT + OFF_XIJ2, lr, lg, col0, acc);
#pragma unroll
    for (int n = 0; n < 4; ++n) bl[n] = xij_b2[col0 + n * 16 + lr];
    unsigned hij_lo[4][4], hij_hi[4][4];
#pragma unroll
    for (int m = 0; m < 4; ++m)
#pragma unroll
        for (int n = 0; n < 4; ++n) {
            hij_lo[m][n] = ((unsigned)f2bf(acc[m][n][1] + bl[n]) << 16) | f2bf(acc[m][n][0] + bl[n]);
            hij_hi[m][n] = ((unsigned)f2bf(acc[m][n][3] + bl[n]) << 16) | f2bf(acc[m][n][2] + bl[n]);
        }
    __syncthreads();   // S2 reads of sH done before S3 overwrites

    // ---- S3: t1 = relu(xcn @ xcn_w1 + b1) -> sH ----
    mfma_stage<64>(sXcn, WT + OFF_XCN1, lr, lg, col0, acc);
#pragma unroll
    for (int n = 0; n < 4; ++n) bl[n] = xcn_b1[col0 + n * 16 + lr];
#pragma unroll
    for (int m = 0; m < 4; ++m)
#pragma unroll
        for (int n = 0; n < 4; ++n)
#pragma unroll
            for (int i = 0; i < 4; ++i) {
                int row = m * 16 + 4 * lg + i;
                int col = col0 + n * 16 + lr;
                sH[row * HID + (col ^ ((row & 7) << 3))] = f2bf(fmaxf(acc[m][n][i] + bl[n], 0.f));
            }
    __syncthreads();

    // ---- S4: t2 = relu(t1 @ xcn_w2 + b2) -> sH in place ----
    mfma_stage<256>(sH, WT + OFF_XCN2, lr, lg, col0, acc);
    __syncthreads();   // all reads done before in-place overwrite
#pragma unroll
    for (int n = 0; n < 4; ++n) bl[n] = xcn_b2[col0 + n * 16 + lr];
#pragma unroll
    for (int m = 0; m < 4; ++m)
#pragma unroll
        for (int n = 0; n < 4; ++n)
#pragma unroll
            for (int i = 0; i < 4; ++i) {
                int row = m * 16 + 4 * lg + i;
                int col = col0 + n * 16 + lr;
                sH[row * HID + (col ^ ((row & 7) << 3))] = f2bf(fmaxf(acc[m][n][i] + bl[n], 0.f));
            }
    __syncthreads();

    // ---- S5: u = (t2 @ xcn_w3 + b3) * beta + h_ij -> sH in place ----
    mfma_stage<256>(sH, WT + OFF_XCN3, lr, lg, col0, acc);
    __syncthreads();
#pragma unroll
    for (int n = 0; n < 4; ++n) bl[n] = xcn_b3[col0 + n * 16 + lr];
    const float betaf = beta[0];
#pragma unroll
    for (int m = 0; m < 4; ++m)
#pragma unroll
        for (int n = 0; n < 4; ++n) {
            float h0 = b2f((unsigned short)(hij_lo[m][n] & 0xFFFF));
            float h1 = b2f((unsigned short)(hij_lo[m][n] >> 16));
            float h2 = b2f((unsigned short)(hij_hi[m][n] & 0xFFFF));
            float h3 = b2f((unsigned short)(hij_hi[m][n] >> 16));
            float v0 = (acc[m][n][0] + bl[n]) * betaf + h0;
            float v1 = (acc[m][n][1] + bl[n]) * betaf + h1;
            float v2 = (acc[m][n][2] + bl[n]) * betaf + h2;
            float v3 = (acc[m][n][3] + bl[n]) * betaf + h3;
            int rb = m * 16 + 4 * lg;
            int col = col0 + n * 16 + lr;
            sH[(rb + 0) * HID + (col ^ (((rb + 0) & 7) << 3))] = f2bf(v0);
            sH[(rb + 1) * HID + (col ^ (((rb + 1) & 7) << 3))] = f2bf(v1);
            sH[(rb + 2) * HID + (col ^ (((rb + 2) & 7) << 3))] = f2bf(v2);
            sH[(rb + 3) * HID + (col ^ (((rb + 3) & 7) << 3))] = f2bf(v3);
        }
    __syncthreads();

    // ---- S6: out = relu(u @ lin_w1 + lb1) . lin_w2 + lb2 ----
    mfma_stage<256>(sH, WT + OFF_LIN1, lr, lg, col0, acc);
#pragma unroll
    for (int n = 0; n < 4; ++n) bl[n] = lin_b1[col0 + n * 16 + lr];
    float w2l[4];
#pragma unroll
    for (int n = 0; n < 4; ++n) w2l[n] = lin_w2[col0 + n * 16 + lr];
#pragma unroll
    for (int m = 0; m < 4; ++m) {
        float p[4] = {0.f, 0.f, 0.f, 0.f};
#pragma unroll
        for (int n = 0; n < 4; ++n)
#pragma unroll
            for (int i = 0; i < 4; ++i)
                p[i] += fmaxf(acc[m][n][i] + bl[n], 0.f) * w2l[n];
#pragma unroll
        for (int i = 0; i < 4; ++i) {
            float s = p[i];
            s += __shfl_xor(s, 1);
            s += __shfl_xor(s, 2);
            s += __shfl_xor(s, 4);
            s += __shfl_xor(s, 8);
            if (lr == 0) sRed[wv * 64 + m * 16 + 4 * lg + i] = s;
        }
    }
    __syncthreads();
    if (tid < 64)
        out[row0 + tid] = sRed[tid] + sRed[64 + tid] + sRed[128 + tid] + sRed[192 + tid] + lin_b2[0];
}

extern "C" void kernel_launch(void* const* d_in, const int* in_sizes, int n_in,
                              void* d_out, int out_size, void* d_ws, size_t ws_size,
                              hipStream_t stream) {
    const float* x      = (const float*)d_in[0];
    const int*   adj    = (const int*)d_in[1];
    const int*   tar    = (const int*)d_in[2];
    const float* beta   = (const float*)d_in[3];
    const float* xcn_w1 = (const float*)d_in[4];
    const float* xcn_b1 = (const float*)d_in[5];
    const float* xcn_w2 = (const float*)d_in[6];
    const float* xcn_b2 = (const float*)d_in[7];
    const float* xcn_w3 = (const float*)d_in[8];
    const float* xcn_b3 = (const float*)d_in[9];
    const float* xij_w1 = (const float*)d_in[10];
    const float* xij_b1 = (const float*)d_in[11];
    const float* xij_w2 = (const float*)d_in[12];
    const float* xij_b2 = (const float*)d_in[13];
    const float* lin_w1 = (const float*)d_in[14];
    const float* lin_b1 = (const float*)d_in[15];
    const float* lin_w2 = (const float*)d_in[16];
    const float* lin_b2 = (const float*)d_in[17];

    unsigned short* WT = (unsigned short*)d_ws;   // 294912 bf16 = 576 KiB

    prep_k<<<WT_TOTAL / 256, 256, 0, stream>>>(xij_w1, xij_w2, xcn_w1, xcn_w2, xcn_w3, lin_w1, WT);
    fused_k<<<NEDGES / 64, 256, 0, stream>>>(x, adj, tar, WT,
                                             xij_b1, xij_b2, xcn_b1, xcn_b2, xcn_b3,
                                             lin_b1, lin_w2, lin_b2, beta, (float*)d_out);
}